// Round 8
// baseline (190.197 us; speedup 1.0000x reference)
//
#include <hip/hip_runtime.h>

// Problem constants
#define NHEADS   8
#define EMB_     128
#define BT_      512        // b*t = 4*128
#define HIN_     1024
#define NQ_      4096       // BT_*NHEADS
#define NKEY_    50000
#define NPAD_    50048      // 782 tiles of 64 keys
#define TILES_TOT 782
#define TPS_     13         // key tiles per slice
#define NSLICES_ 61         // 60 full + 1 slice of 2 tiles; grid 16x61

#define PROJ_BLOCKS 512
#define CONV_BLOCKS ((NPAD_ * 16) / 256)   // 3128

// scale = 128^-0.25 (reference) * log2(e) (scores land directly in exp2 domain)
#define QSCALE   (0.29730177875068026f * 1.4426950408889634f)
#define SHIFT_   44.0f      // fixed softmax shift in log2 domain (> max score)

typedef __attribute__((ext_vector_type(8))) short short8v;   // 8 bf16 = 4 VGPRs (MFMA A/B frag)
typedef __attribute__((ext_vector_type(4))) float float4v;   // MFMA C/D frag

#if __has_builtin(__builtin_amdgcn_exp2f)
#define EXP2F(x) __builtin_amdgcn_exp2f(x)
#else
#define EXP2F(x) exp2f(x)
#endif

__device__ __forceinline__ short f2bf(float f) {  // fp32 -> bf16 bits, RNE
  unsigned u = __float_as_uint(f);
  u += 0x7fffu + ((u >> 16) & 1u);
  return (short)(u >> 16);
}

// packed fp32x2 -> bf16x2 (gfx950 v_cvt_pk_bf16_f32 when available)
#if __has_builtin(__builtin_amdgcn_cvt_pk_bf16_f32)
typedef __attribute__((ext_vector_type(2))) __bf16 bf16x2;
__device__ __forceinline__ unsigned pk2(float a, float b) {
  bf16x2 r = __builtin_amdgcn_cvt_pk_bf16_f32(a, b);
  union { bf16x2 v; unsigned u; } c; c.v = r; return c.u;
}
#else
__device__ __forceinline__ unsigned pk2(float a, float b) {
  return (unsigned)(unsigned short)f2bf(a) | ((unsigned)(unsigned short)f2bf(b) << 16);
}
#endif

// ---------------------------------------------------------------------------
// Kernel 0 (fused prep) -- unchanged from r7. Blocks [0,512) = q-projection
// (MFMA, 2-stage register pipeline); blocks [512, +3128) = keys fp32->bf16
// with store-side XOR chunk swizzle (dense loads, permuted 16B stores).
// ---------------------------------------------------------------------------
__global__ __launch_bounds__(256, 1) void prep_kernel(
    const float* __restrict__ x, const float* __restrict__ Wq,
    short* __restrict__ qb,
    const float* __restrict__ keys, const float* __restrict__ values,
    short* __restrict__ keys_sw, float* __restrict__ vpad) {
  if (blockIdx.x < PROJ_BLOCKS) {
    const int wave = threadIdx.x >> 6, lane = threadIdx.x & 63;
    const int quad = lane >> 4, ln = lane & 15;
    const int tile = blockIdx.x * 4 + wave;      // 2048 tiles
    const int mt = tile >> 6, ot = tile & 63;    // 32 m-tiles x 64 o-tiles
    const float* xrow = x  + (mt * 16 + ln) * HIN_ + quad * 8;
    const float* wrow = Wq + (ot * 16 + ln) * HIN_ + quad * 8;
    float4v d = {0.f, 0.f, 0.f, 0.f};

    float4 xc[2][2], wc[2][2];
#pragma unroll
    for (int s = 0; s < 2; ++s) {
      xc[s][0] = *(const float4*)(xrow + s * 32);
      xc[s][1] = *(const float4*)(xrow + s * 32 + 4);
      wc[s][0] = *(const float4*)(wrow + s * 32);
      wc[s][1] = *(const float4*)(wrow + s * 32 + 4);
    }
#pragma unroll
    for (int it = 0; it < 32; ++it) {            // k-chunk = 32 floats
      const int s = it & 1;
      float4 xa = xc[s][0], xb = xc[s][1];
      float4 wa = wc[s][0], wb = wc[s][1];
      const int kn = (it + 2) * 32;
      if (kn < HIN_) {
        xc[s][0] = *(const float4*)(xrow + kn);
        xc[s][1] = *(const float4*)(xrow + kn + 4);
        wc[s][0] = *(const float4*)(wrow + kn);
        wc[s][1] = *(const float4*)(wrow + kn + 4);
      }
      union { short8v s8; unsigned u[4]; } af, bf;
      af.u[0] = pk2(xa.x, xa.y); af.u[1] = pk2(xa.z, xa.w);
      af.u[2] = pk2(xb.x, xb.y); af.u[3] = pk2(xb.z, xb.w);
      bf.u[0] = pk2(wa.x, wa.y); bf.u[1] = pk2(wa.z, wa.w);
      bf.u[2] = pk2(wb.x, wb.y); bf.u[3] = pk2(wb.z, wb.w);
      d = __builtin_amdgcn_mfma_f32_16x16x32_bf16(af.s8, bf.s8, d, 0, 0, 0);
    }
#pragma unroll
    for (int r2 = 0; r2 < 4; ++r2)
      qb[(mt * 16 + quad * 4 + r2) * HIN_ + ot * 16 + ln] = f2bf(d[r2] * QSCALE);
  } else {
    int idx = (blockIdx.x - PROJ_BLOCKS) * 256 + threadIdx.x;
    int key = idx >> 4;
    int lc  = idx & 15;
    union { short8v s; unsigned u[4]; } o;
    if (key < NKEY_) {
      const float4* src = (const float4*)(keys + key * EMB_ + lc * 8);
      float4 v0 = src[0], v1 = src[1];
      o.u[0] = pk2(v0.x, v0.y); o.u[1] = pk2(v0.z, v0.w);
      o.u[2] = pk2(v1.x, v1.y); o.u[3] = pk2(v1.z, v1.w);
    } else {
      o.u[0] = 0; o.u[1] = 0; o.u[2] = 0; o.u[3] = 0;
    }
    int pc = lc ^ (key & 15);                    // physical chunk (involution)
    *(short8v*)(keys_sw + (key * 16 + pc) * 8) = o.s;
    if (lc == 0) vpad[key] = (key < NKEY_) ? values[key] : 0.f;
  }
}

// ---------------------------------------------------------------------------
// Kernel 1: flash-decoding attention, RESTRUCTURED for register occupancy.
// r1-r7 post-mortem: occupancy pinned at ~17.5% (2 waves/SIMD) because true
// per-wave regs (arch+acc, unified file) ~142 > the 128 cliff (m69) -- which
// is why every scheduling tweak was flat at ~76 us. This version: 512-thread
// blocks (8 waves), 2 query-sub-tiles per wave -> a[2][4]=32 + stage[2]=8 +
// b[4]=16 + sums=16 + d=4 + addr ~ 88 regs total -> 4+ waves/SIMD. Block
// still covers 256 queries; grid and staging traffic unchanged.
// ---------------------------------------------------------------------------
__global__ __launch_bounds__(512) void attn_kernel(
    const short* __restrict__ qb,        // bf16 [NQ_][128]
    const short* __restrict__ keys_sw,   // bf16 [NPAD_][128], chunk-swizzled
    const float* __restrict__ vpad,      // [NPAD_]
    float* __restrict__ partials) {      // [NQ_][NSLICES_][2] = {l, acc}
  __shared__ __align__(16) short kt[2][64 * 128];   // 2 x 16 KB ping-pong
  const int t     = threadIdx.x;                 // 0..511
  const int wave  = t >> 6;                      // 0..7
  const int lane  = t & 63;
  const int quad  = lane >> 4;
  const int ln    = lane & 15;
  const int qbase = blockIdx.x * 256 + wave * 32;  // 2 sub-tiles of 16
  const int slice = blockIdx.y;
  const int tile0 = slice * TPS_;
  const int tile1 = (tile0 + TPS_ < TILES_TOT) ? (tile0 + TPS_) : TILES_TOT;

  short8v a[2][4];                               // 32 VGPRs
#pragma unroll
  for (int sub = 0; sub < 2; ++sub)
#pragma unroll
    for (int ks = 0; ks < 4; ++ks)
      a[sub][ks] = *(const short8v*)(qb + (qbase + sub * 16 + ln) * EMB_ + ks * 32 + quad * 8);

  float lsum[2][4], asum[2][4];
#pragma unroll
  for (int i = 0; i < 2; ++i)
#pragma unroll
    for (int j = 0; j < 4; ++j) { lsum[i][j] = 0.f; asum[i][j] = 0.f; }

  short8v stage[2];                              // 32 B/thread prefetch window
  {                                              // preload tile0 -> buf0
    const short* src = keys_sw + tile0 * (64 * 128);
#pragma unroll
    for (int j = 0; j < 2; ++j)
      stage[j] = *(const short8v*)(src + (t + j * 512) * 8);
#pragma unroll
    for (int j = 0; j < 2; ++j)
      *(short8v*)(&kt[0][0] + (t + j * 512) * 8) = stage[j];
    const short* s1 = keys_sw + (tile0 + 1) * (64 * 128);  // prefetch tile0+1
#pragma unroll
    for (int j = 0; j < 2; ++j)                  // (tile0+1 <= 781: in-bank)
      stage[j] = *(const short8v*)(s1 + (t + j * 512) * 8);
  }
  __syncthreads();

  for (int tile = tile0; tile < tile1; ++tile) {
    const int cur = (tile - tile0) & 1;
    if (tile + 1 < tile1) {                      // park prefetched tile+1
#pragma unroll
      for (int j = 0; j < 2; ++j)
        *(short8v*)(&kt[cur ^ 1][0] + (t + j * 512) * 8) = stage[j];
    }
    if (tile + 2 < tile1) {                      // issue tile+2 loads now
      const short* nsrc = keys_sw + (tile + 2) * (64 * 128);
#pragma unroll
      for (int j = 0; j < 2; ++j)
        stage[j] = *(const short8v*)(nsrc + (t + j * 512) * 8);
    }
#pragma unroll
    for (int nsub = 0; nsub < 4; ++nsub) {
      short8v b[4];
#pragma unroll
      for (int ks = 0; ks < 4; ++ks) {
        int kc = ks * 4 + quad;                  // logical 8-elem chunk
        b[ks] = *(const short8v*)(&kt[cur][0] + (nsub * 16 + ln) * EMB_ + ((kc ^ ln) * 8));
      }
      float v = vpad[tile * 64 + nsub * 16 + ln];
#pragma unroll
      for (int sub = 0; sub < 2; ++sub) {
        float4v d = {-SHIFT_, -SHIFT_, -SHIFT_, -SHIFT_};
#pragma unroll
        for (int ks = 0; ks < 4; ++ks)
          d = __builtin_amdgcn_mfma_f32_16x16x32_bf16(a[sub][ks], b[ks], d, 0, 0, 0);
#pragma unroll
        for (int r2 = 0; r2 < 4; ++r2) {
          float p = EXP2F(d[r2]);
          lsum[sub][r2] += p;
          asum[sub][r2] = fmaf(p, v, asum[sub][r2]);
        }
      }
    }
    __syncthreads();
  }

  // reduce over the 16 key-column lanes (same quad); lane ln==0 writes
#pragma unroll
  for (int sub = 0; sub < 2; ++sub)
#pragma unroll
    for (int r2 = 0; r2 < 4; ++r2) {
      float L = lsum[sub][r2], A = asum[sub][r2];
#pragma unroll
      for (int m = 1; m < 16; m <<= 1) {
        L += __shfl_xor(L, m, 64);
        A += __shfl_xor(A, m, 64);
      }
      if (ln == 0) {
        int q = qbase + sub * 16 + quad * 4 + r2;
        partials[(q * NSLICES_ + slice) * 2 + 0] = L;
        partials[(q * NSLICES_ + slice) * 2 + 1] = A;
      }
    }
}

// ---------------------------------------------------------------------------
// Kernel 2: combine slice partials, mean over heads, add curiosity.
// 61 slices * 2 floats = 122 = 30 float4 + 2 scalars.
// ---------------------------------------------------------------------------
__global__ __launch_bounds__(256) void finalize_kernel(
    const float* __restrict__ partials, const float* __restrict__ cur,
    float* __restrict__ out) {
  int tid = blockIdx.x * 256 + threadIdx.x;      // 4096 threads
  int bt = tid >> 3, h = tid & 7;
  int q = bt * NHEADS + h;
  const float* base = partials + q * NSLICES_ * 2;
  const float4* p = (const float4*)base;
  float sl = 0.f, sa = 0.f;
#pragma unroll
  for (int i = 0; i < (NSLICES_ * 2) / 4; ++i) { // 30 float4
    float4 v = p[i];
    sl += v.x + v.z;
    sa += v.y + v.w;
  }
  sl += base[NSLICES_ * 2 - 2];                  // tail slice 60
  sa += base[NSLICES_ * 2 - 1];
  float r = sa / sl;
  r += __shfl_xor(r, 1, 64);
  r += __shfl_xor(r, 2, 64);
  r += __shfl_xor(r, 4, 64);
  if (h == 0) out[bt] = r * (1.f / NHEADS) + cur[bt];
}

// ---------------------------------------------------------------------------
extern "C" void kernel_launch(void* const* d_in, const int* in_sizes, int n_in,
                              void* d_out, int out_size, void* d_ws, size_t ws_size,
                              hipStream_t stream) {
  (void)in_sizes; (void)n_in; (void)out_size; (void)ws_size;
  const float* x      = (const float*)d_in[0];   // (4,128,1024)
  const float* cur    = (const float*)d_in[1];   // (4,128)
  const float* Wq     = (const float*)d_in[2];   // (1024,1024)
  const float* keys   = (const float*)d_in[3];   // (50000,128)
  const float* values = (const float*)d_in[4];   // (50000,)
  float* out = (float*)d_out;                    // (4,128,1) fp32

  // workspace layout (16B-aligned), 16,059,904 B total
  char* ws = (char*)d_ws;
  short* keys_sw = (short*)(ws);                        // 12,812,288 B
  float* vpad    = (float*)(ws + 12812288);             //    200,192 B
  short* qb      = (short*)(ws + 13012480);             //  1,048,576 B
  float* part    = (float*)(ws + 14061056);             //  1,998,848 B (61 slices)

  hipLaunchKernelGGL(prep_kernel, dim3(PROJ_BLOCKS + CONV_BLOCKS), dim3(256), 0, stream,
                     x, Wq, qb, keys, values, keys_sw, vpad);
  hipLaunchKernelGGL(attn_kernel, dim3(16, NSLICES_), dim3(512), 0, stream,
                     qb, keys_sw, vpad, part);
  hipLaunchKernelGGL(finalize_kernel, dim3(16), dim3(256), 0, stream, part, cur, out);
}

// Round 9
// 180.463 us; speedup vs baseline: 1.0539x; 1.0539x over previous
//
#include <hip/hip_runtime.h>

// Problem constants
#define NHEADS   8
#define EMB_     128
#define BT_      512        // b*t = 4*128
#define HIN_     1024
#define NQ_      4096       // BT_*NHEADS
#define NKEY_    50000
#define NPAD_    50048      // 782 tiles of 64 keys
#define TILES_TOT 782
#define TPS_     17         // key tiles per slice: 46*17 = 782 exactly
#define NSLICES_ 46         // grid 16x46 = 736 blocks (r6 best: 74.7 us)

// scale = 128^-0.25 (reference) * log2(e) (scores land directly in exp2 domain)
#define QSCALE   (0.29730177875068026f * 1.4426950408889634f)
#define SHIFT_   44.0f      // fixed softmax shift in log2 domain (> max score)

typedef __attribute__((ext_vector_type(8))) short short8v;   // 8 bf16 = 4 VGPRs (MFMA A/B frag)
typedef __attribute__((ext_vector_type(4))) float float4v;   // MFMA C/D frag

#if __has_builtin(__builtin_amdgcn_exp2f)
#define EXP2F(x) __builtin_amdgcn_exp2f(x)
#else
#define EXP2F(x) exp2f(x)
#endif

__device__ __forceinline__ short f2bf(float f) {  // fp32 -> bf16 bits, RNE
  unsigned u = __float_as_uint(f);
  u += 0x7fffu + ((u >> 16) & 1u);
  return (short)(u >> 16);
}

// packed fp32x2 -> bf16x2 (gfx950 v_cvt_pk_bf16_f32 when available)
#if __has_builtin(__builtin_amdgcn_cvt_pk_bf16_f32)
typedef __attribute__((ext_vector_type(2))) __bf16 bf16x2;
__device__ __forceinline__ unsigned pk2(float a, float b) {
  bf16x2 r = __builtin_amdgcn_cvt_pk_bf16_f32(a, b);
  union { bf16x2 v; unsigned u; } c; c.v = r; return c.u;
}
#else
__device__ __forceinline__ unsigned pk2(float a, float b) {
  return (unsigned)(unsigned short)f2bf(a) | ((unsigned)(unsigned short)f2bf(b) << 16);
}
#endif

// ---------------------------------------------------------------------------
// Kernel 0: keys fp32 -> bf16, store-side XOR chunk swizzle (r6 version).
// Dense float4 loads; 16B stores permuted within each 256B row. Physical
// chunk p of row key holds logical chunk p^(key&15) (involution), making the
// attention B-frag ds_read_b128 2-way max (free, m136).
// ---------------------------------------------------------------------------
__global__ __launch_bounds__(256) void convert_kernel(
    const float* __restrict__ keys, const float* __restrict__ values,
    short* __restrict__ keys_sw, float* __restrict__ vpad) {
  int idx = blockIdx.x * 256 + threadIdx.x;      // logical 8-elem chunk id
  int key = idx >> 4;
  int lc  = idx & 15;
  union { short8v s; unsigned u[4]; } o;
  if (key < NKEY_) {
    const float4* src = (const float4*)(keys + key * EMB_ + lc * 8);
    float4 v0 = src[0], v1 = src[1];
    o.u[0] = pk2(v0.x, v0.y); o.u[1] = pk2(v0.z, v0.w);
    o.u[2] = pk2(v1.x, v1.y); o.u[3] = pk2(v1.z, v1.w);
  } else {
    o.u[0] = 0; o.u[1] = 0; o.u[2] = 0; o.u[3] = 0;  // pad rows -> p=2^-44
  }
  int pc = lc ^ (key & 15);                      // physical chunk (involution)
  *(short8v*)(keys_sw + (key * 16 + pc) * 8) = o.s;
  if (lc == 0) vpad[key] = (key < NKEY_) ? values[key] : 0.f;
}

// ---------------------------------------------------------------------------
// Kernel 1: q = (x @ Wq^T) * QSCALE -> bf16. FIXED this round: r5-r8's proj
// was the invisible ~65 us pig (cross-round residue ledger + r4's direct
// prep=117 measurement). Cause: dynamically-indexed xc[s][..] buffers +
// (256,1) full-unroll => load-hoist register explosion (1 wave/SIMD or
// scratch spill). This version: ROLLED loop (#pragma unroll 1), explicit
// double-buffer in NAMED scalars (static register assignment), default
// register budget. ~90 VGPR demand -> 5 waves/SIMD; 1-iteration prefetch
// distance x 5 waves covers L2 latency.
// ---------------------------------------------------------------------------
__global__ __launch_bounds__(256) void proj_kernel(
    const float* __restrict__ x, const float* __restrict__ Wq,
    short* __restrict__ qb) {
  const int wave = threadIdx.x >> 6, lane = threadIdx.x & 63;
  const int quad = lane >> 4, ln = lane & 15;
  const int tile = blockIdx.x * 4 + wave;        // 2048 tiles
  const int mt = tile >> 6, ot = tile & 63;      // 32 m-tiles x 64 o-tiles
  const float* xrow = x  + (mt * 16 + ln) * HIN_ + quad * 8;
  const float* wrow = Wq + (ot * 16 + ln) * HIN_ + quad * 8;
  float4v d = {0.f, 0.f, 0.f, 0.f};

  // buffer A = chunk k0, buffer B = chunk k0+32 (named scalars, no arrays)
  float4 xa0 = *(const float4*)(xrow);
  float4 xa1 = *(const float4*)(xrow + 4);
  float4 wa0 = *(const float4*)(wrow);
  float4 wa1 = *(const float4*)(wrow + 4);
  float4 xb0 = *(const float4*)(xrow + 32);
  float4 xb1 = *(const float4*)(xrow + 36);
  float4 wb0 = *(const float4*)(wrow + 32);
  float4 wb1 = *(const float4*)(wrow + 36);

#pragma unroll 1
  for (int k0 = 0; k0 < HIN_; k0 += 64) {
    // ---- consume buffer A (chunk k0) ----
    union { short8v s8; unsigned u[4]; } af, bf;
    af.u[0] = pk2(xa0.x, xa0.y); af.u[1] = pk2(xa0.z, xa0.w);
    af.u[2] = pk2(xa1.x, xa1.y); af.u[3] = pk2(xa1.z, xa1.w);
    bf.u[0] = pk2(wa0.x, wa0.y); bf.u[1] = pk2(wa0.z, wa0.w);
    bf.u[2] = pk2(wa1.x, wa1.y); bf.u[3] = pk2(wa1.z, wa1.w);
    if (k0 + 64 < HIN_) {                        // refill A with chunk k0+64
      xa0 = *(const float4*)(xrow + k0 + 64);
      xa1 = *(const float4*)(xrow + k0 + 68);
      wa0 = *(const float4*)(wrow + k0 + 64);
      wa1 = *(const float4*)(wrow + k0 + 68);
    }
    d = __builtin_amdgcn_mfma_f32_16x16x32_bf16(af.s8, bf.s8, d, 0, 0, 0);

    // ---- consume buffer B (chunk k0+32) ----
    af.u[0] = pk2(xb0.x, xb0.y); af.u[1] = pk2(xb0.z, xb0.w);
    af.u[2] = pk2(xb1.x, xb1.y); af.u[3] = pk2(xb1.z, xb1.w);
    bf.u[0] = pk2(wb0.x, wb0.y); bf.u[1] = pk2(wb0.z, wb0.w);
    bf.u[2] = pk2(wb1.x, wb1.y); bf.u[3] = pk2(wb1.z, wb1.w);
    if (k0 + 96 < HIN_) {                        // refill B with chunk k0+96
      xb0 = *(const float4*)(xrow + k0 + 96);
      xb1 = *(const float4*)(xrow + k0 + 100);
      wb0 = *(const float4*)(wrow + k0 + 96);
      wb1 = *(const float4*)(wrow + k0 + 100);
    }
    d = __builtin_amdgcn_mfma_f32_16x16x32_bf16(af.s8, bf.s8, d, 0, 0, 0);
  }
#pragma unroll
  for (int r2 = 0; r2 < 4; ++r2)
    qb[(mt * 16 + quad * 4 + r2) * HIN_ + ot * 16 + ln] = f2bf(d[r2] * QSCALE);
}

// ---------------------------------------------------------------------------
// Kernel 2: flash-decoding attention -- EXACT r6 revert (74.7 us best).
// Grid (16 query-cols, 46 key-slices), 256 thr, ping-pong LDS, one barrier
// per tile, register prefetch 2 tiles ahead.
// ---------------------------------------------------------------------------
__global__ __launch_bounds__(256) void attn_kernel(
    const short* __restrict__ qb,        // bf16 [NQ_][128]
    const short* __restrict__ keys_sw,   // bf16 [NPAD_][128], chunk-swizzled
    const float* __restrict__ vpad,      // [NPAD_]
    float* __restrict__ partials) {      // [NQ_][NSLICES_][2] = {l, acc}
  __shared__ __align__(16) short kt[2][64 * 128];   // 2 x 16 KB ping-pong
  const int t     = threadIdx.x;
  const int wave  = t >> 6;
  const int lane  = t & 63;
  const int quad  = lane >> 4;
  const int ln    = lane & 15;
  const int qbase = blockIdx.x * 256 + wave * 64;
  const int slice = blockIdx.y;
  const int tile0 = slice * TPS_;
  const int tile1 = tile0 + TPS_;                // all slices full (46*17=782)

  short8v a[4][4];
#pragma unroll
  for (int sub = 0; sub < 4; ++sub)
#pragma unroll
    for (int ks = 0; ks < 4; ++ks)
      a[sub][ks] = *(const short8v*)(qb + (qbase + sub * 16 + ln) * EMB_ + ks * 32 + quad * 8);

  float lsum[4][4], asum[4][4];
#pragma unroll
  for (int i = 0; i < 4; ++i)
#pragma unroll
    for (int j = 0; j < 4; ++j) { lsum[i][j] = 0.f; asum[i][j] = 0.f; }

  short8v stage[4];                              // 64 B/thread prefetch window
  {                                              // preload tile0 -> buf0
    const short* src = keys_sw + tile0 * (64 * 128);
#pragma unroll
    for (int j = 0; j < 4; ++j)
      stage[j] = *(const short8v*)(src + (t + j * 256) * 8);
#pragma unroll
    for (int j = 0; j < 4; ++j)
      *(short8v*)(&kt[0][0] + (t + j * 256) * 8) = stage[j];
    const short* s1 = keys_sw + (tile0 + 1) * (64 * 128);  // prefetch tile0+1
#pragma unroll
    for (int j = 0; j < 4; ++j)
      stage[j] = *(const short8v*)(s1 + (t + j * 256) * 8);
  }
  __syncthreads();

  for (int tile = tile0; tile < tile1; ++tile) {
    const int cur = (tile - tile0) & 1;
    if (tile + 1 < tile1) {                      // park prefetched tile+1
#pragma unroll
      for (int j = 0; j < 4; ++j)
        *(short8v*)(&kt[cur ^ 1][0] + (t + j * 256) * 8) = stage[j];
    }
    if (tile + 2 < tile1) {                      // issue tile+2 loads now
      const short* nsrc = keys_sw + (tile + 2) * (64 * 128);
#pragma unroll
      for (int j = 0; j < 4; ++j)
        stage[j] = *(const short8v*)(nsrc + (t + j * 256) * 8);
    }
#pragma unroll
    for (int nsub = 0; nsub < 4; ++nsub) {
      short8v b[4];
#pragma unroll
      for (int ks = 0; ks < 4; ++ks) {
        int kc = ks * 4 + quad;                  // logical 8-elem chunk
        b[ks] = *(const short8v*)(&kt[cur][0] + (nsub * 16 + ln) * EMB_ + ((kc ^ ln) * 8));
      }
      float v = vpad[tile * 64 + nsub * 16 + ln];
#pragma unroll
      for (int sub = 0; sub < 4; ++sub) {
        float4v d = {-SHIFT_, -SHIFT_, -SHIFT_, -SHIFT_};
#pragma unroll
        for (int ks = 0; ks < 4; ++ks)
          d = __builtin_amdgcn_mfma_f32_16x16x32_bf16(a[sub][ks], b[ks], d, 0, 0, 0);
#pragma unroll
        for (int r2 = 0; r2 < 4; ++r2) {
          float p = EXP2F(d[r2]);
          lsum[sub][r2] += p;
          asum[sub][r2] = fmaf(p, v, asum[sub][r2]);
        }
      }
    }
    __syncthreads();
  }

#pragma unroll
  for (int sub = 0; sub < 4; ++sub)
#pragma unroll
    for (int r2 = 0; r2 < 4; ++r2) {
      float L = lsum[sub][r2], A = asum[sub][r2];
#pragma unroll
      for (int m = 1; m < 16; m <<= 1) {
        L += __shfl_xor(L, m, 64);
        A += __shfl_xor(A, m, 64);
      }
      if (ln == 0) {
        int q = qbase + sub * 16 + quad * 4 + r2;
        partials[(q * NSLICES_ + slice) * 2 + 0] = L;
        partials[(q * NSLICES_ + slice) * 2 + 1] = A;
      }
    }
}

// ---------------------------------------------------------------------------
// Kernel 3: combine slice partials, mean over heads, add curiosity.
// 46 slices * 2 floats = 23 float4 per (bt,head).
// ---------------------------------------------------------------------------
__global__ __launch_bounds__(256) void finalize_kernel(
    const float* __restrict__ partials, const float* __restrict__ cur,
    float* __restrict__ out) {
  int tid = blockIdx.x * 256 + threadIdx.x;      // 4096 threads
  int bt = tid >> 3, h = tid & 7;
  int q = bt * NHEADS + h;
  const float4* p = (const float4*)(partials + q * NSLICES_ * 2);
  float sl = 0.f, sa = 0.f;
#pragma unroll
  for (int i = 0; i < NSLICES_ / 2; ++i) {       // 2 slices per float4
    float4 v = p[i];
    sl += v.x + v.z;
    sa += v.y + v.w;
  }
  float r = sa / sl;
  r += __shfl_xor(r, 1, 64);
  r += __shfl_xor(r, 2, 64);
  r += __shfl_xor(r, 4, 64);
  if (h == 0) out[bt] = r * (1.f / NHEADS) + cur[bt];
}

// ---------------------------------------------------------------------------
extern "C" void kernel_launch(void* const* d_in, const int* in_sizes, int n_in,
                              void* d_out, int out_size, void* d_ws, size_t ws_size,
                              hipStream_t stream) {
  (void)in_sizes; (void)n_in; (void)out_size; (void)ws_size;
  const float* x      = (const float*)d_in[0];   // (4,128,1024)
  const float* cur    = (const float*)d_in[1];   // (4,128)
  const float* Wq     = (const float*)d_in[2];   // (1024,1024)
  const float* keys   = (const float*)d_in[3];   // (50000,128)
  const float* values = (const float*)d_in[4];   // (50000,)
  float* out = (float*)d_out;                    // (4,128,1) fp32

  // workspace layout (16B-aligned), ~15.6 MB total
  char* ws = (char*)d_ws;
  short* keys_sw = (short*)(ws);                        // 12,812,288 B
  float* vpad    = (float*)(ws + 12812288);             //    200,192 B
  short* qb      = (short*)(ws + 13012480);             //  1,048,576 B
  float* part    = (float*)(ws + 14061056);             //  1,507,328 B (46 slices)

  hipLaunchKernelGGL(convert_kernel, dim3((NPAD_ * 16) / 256), dim3(256), 0, stream,
                     keys, values, keys_sw, vpad);
  hipLaunchKernelGGL(proj_kernel, dim3(512), dim3(256), 0, stream, x, Wq, qb);
  hipLaunchKernelGGL(attn_kernel, dim3(16, NSLICES_), dim3(256), 0, stream,
                     qb, keys_sw, vpad, part);
  hipLaunchKernelGGL(finalize_kernel, dim3(16), dim3(256), 0, stream, part, cur, out);
}